// Round 9
// baseline (285.946 us; speedup 1.0000x reference)
//
#include <hip/hip_runtime.h>
#include <stdint.h>

#define DM 1024      // d_model
#define HEADS 16
#define BATCH 8
#define SEQ 1024
#define MTOT 8192    // BATCH*SEQ

typedef _Float16 half8 __attribute__((ext_vector_type(8)));
typedef _Float16 half4 __attribute__((ext_vector_type(4)));
typedef float floatx4 __attribute__((ext_vector_type(4)));

// async global->LDS, 16B per lane. lds dest must be wave-uniform base; HW adds lane*16.
__device__ __forceinline__ void glds16(const void* g, void* l) {
    __builtin_amdgcn_global_load_lds(
        (const __attribute__((address_space(1))) void*)g,
        (__attribute__((address_space(3))) void*)l, 16, 0, 0);
}

// ---------------------------------------------------------------------------
// Fused prep: blocks [0,12288) convert Q/K/V fp32->fp16 (8 elems/thread);
// blocks [12288,15360) transpose+convert W[K][N] fp32 -> Wt[N][K] fp16.
__global__ __launch_bounds__(256) void prep(
        const float* __restrict__ Q, const float* __restrict__ K,
        const float* __restrict__ V,
        _Float16* __restrict__ qb, _Float16* __restrict__ kb, _Float16* __restrict__ vb,
        const float* __restrict__ Wq, const float* __restrict__ Wk,
        const float* __restrict__ Wv,
        _Float16* __restrict__ wqt, _Float16* __restrict__ wkt, _Float16* __restrict__ wvt) {
    __shared__ float t[32][33];
    int bid = blockIdx.x, tid = threadIdx.x;
    if (bid < 12288) {
        int ten = bid >> 12;              // 0,1,2
        int bx  = bid & 4095;
        const float* src = ten == 0 ? Q : (ten == 1 ? K : V);
        _Float16* dst    = ten == 0 ? qb : (ten == 1 ? kb : vb);
        size_t i = ((size_t)bx * 256 + tid) * 8;
        float4 a = *(const float4*)(src + i);
        float4 b = *(const float4*)(src + i + 4);
        half8 h;
        h[0] = (_Float16)a.x; h[1] = (_Float16)a.y; h[2] = (_Float16)a.z; h[3] = (_Float16)a.w;
        h[4] = (_Float16)b.x; h[5] = (_Float16)b.y; h[6] = (_Float16)b.z; h[7] = (_Float16)b.w;
        *(half8*)(dst + i) = h;
    } else {
        int wb = bid - 12288;             // [0, 3072)
        int z  = wb >> 10;                // 0,1,2
        int rem = wb & 1023;
        const float* W = z == 0 ? Wq : (z == 1 ? Wk : Wv);
        _Float16* Wt   = z == 0 ? wqt : (z == 1 ? wkt : wvt);
        int k0 = (rem & 31) * 32, n0 = (rem >> 5) * 32;
        int tx = tid & 31, ty = tid >> 5;
#pragma unroll
        for (int i = 0; i < 4; i++)
            t[ty + i * 8][tx] = W[(size_t)(k0 + ty + i * 8) * DM + n0 + tx];
        __syncthreads();
#pragma unroll
        for (int i = 0; i < 4; i++)
            Wt[(size_t)(n0 + ty + i * 8) * DM + k0 + tx] = (_Float16)t[tx][ty + i * 8];
    }
}

// ---------------------------------------------------------------------------
// Projection GEMM: C[8192,1024] = A[8192,1024] @ W[1024,1024] + bias.
// 256x128 tile, 512 thr (8 waves as 4M x 2N, per-wave 64x64 -> acc 4x4,
// SAME register shape as the proven 128^2 kernel, ~116 VGPR demand, no spill
// even under the 512-thread 128-VGPR cap observed in rounds 5-6).
// Depth-1 glds16-only dbuf (proven r7): per K-tile issue stage(t+1) into
// buf^1 FIRST, then frag-read + 32 MFMA/wave on buf, then ONE __syncthreads.
// Staging issues/wave/tile: A 4 + B 2 = 6 (was 8). LDS 96KB -> 1 blk/CU
// (8 waves/CU, same as r7's 2x4-wave blocks). grid (32,8,3) = 768 = 3 clean
// full-CU rounds.
// z<2: MFMA operand order swapped (A-op = W-frag) so accumulator rows = d
//      (consecutive) -> packed 8B stores to [b][h][s][d].
// z=2: original order, accumulator rows = s -> packed 8B stores to vT [b][h][d][s].
__global__ __launch_bounds__(512) void proj_gemm(
        const _Float16* __restrict__ qb, const _Float16* __restrict__ kb,
        const _Float16* __restrict__ vb,
        const _Float16* __restrict__ wqt, const _Float16* __restrict__ wkt,
        const _Float16* __restrict__ wvt,
        const float* __restrict__ bq, const float* __restrict__ bk,
        const float* __restrict__ bv,
        _Float16* __restrict__ qh, _Float16* __restrict__ kh, _Float16* __restrict__ vT) {
    __shared__ _Float16 As[2][256 * 64];   // 64 KB
    __shared__ _Float16 Bs[2][128 * 64];   // 32 KB
    int z = blockIdx.z;
    const _Float16* A  = z == 0 ? qb : (z == 1 ? kb : vb);
    const _Float16* Bw = z == 0 ? wqt : (z == 1 ? wkt : wvt);
    const float* bias  = z == 0 ? bq : (z == 1 ? bk : bv);
    int m0 = blockIdx.x * 256, n0 = blockIdx.y * 128;
    int tid = threadIdx.x, wid = tid >> 6, lane = tid & 63;
    int l15 = lane & 15, quad = lane >> 4;
    int wm = wid >> 1, wn = wid & 1;       // 4M x 2N of 64x64
    bool swapped = (z < 2);

    int srow = lane >> 3;                  // row within an 8-row stage chunk
    int pg = (lane & 7) ^ srow;            // pre-swizzled global 16B chunk

    floatx4 acc[4][4] = {};

    // ---- prologue: stage K-tile 0 into buf 0 ----
#pragma unroll
    for (int ii = 0; ii < 4; ii++) {
        int ia = wid * 4 + ii;             // A issues: 32 total -> 256 rows
        glds16(A + (size_t)(m0 + ia * 8 + srow) * DM + pg * 8, &As[0][ia * 512]);
    }
#pragma unroll
    for (int jj = 0; jj < 2; jj++) {
        int ib = wid * 2 + jj;             // B issues: 16 total -> 128 rows
        glds16(Bw + (size_t)(n0 + ib * 8 + srow) * DM + pg * 8, &Bs[0][ib * 512]);
    }
    __syncthreads();

    for (int t = 0; t < 16; t++) {
        int cur = t & 1;

        // ---- issue next-tile stage first (latency hides under compute) ----
        if (t < 15) {
            int k0 = (t + 1) * 64;
#pragma unroll
            for (int ii = 0; ii < 4; ii++) {
                int ia = wid * 4 + ii;
                glds16(A + (size_t)(m0 + ia * 8 + srow) * DM + k0 + pg * 8,
                       &As[cur ^ 1][ia * 512]);
            }
#pragma unroll
            for (int jj = 0; jj < 2; jj++) {
                int ib = wid * 2 + jj;
                glds16(Bw + (size_t)(n0 + ib * 8 + srow) * DM + k0 + pg * 8,
                       &Bs[cur ^ 1][ib * 512]);
            }
        }

        // ---- compute current tile ----
#pragma unroll
        for (int kc = 0; kc < 2; kc++) {
            half8 a[4], b[4];
#pragma unroll
            for (int mt = 0; mt < 4; mt++) {
                int row = wm * 64 + mt * 16 + l15;
                int pl = (kc * 4 + quad) ^ (l15 & 7);
                a[mt] = *(const half8*)&As[cur][row * 64 + pl * 8];
            }
#pragma unroll
            for (int nt = 0; nt < 4; nt++) {
                int row = wn * 64 + nt * 16 + l15;
                int pl = (kc * 4 + quad) ^ (l15 & 7);
                b[nt] = *(const half8*)&Bs[cur][row * 64 + pl * 8];
            }
            if (swapped) {
#pragma unroll
                for (int mt = 0; mt < 4; mt++)
#pragma unroll
                    for (int nt = 0; nt < 4; nt++)
                        acc[mt][nt] = __builtin_amdgcn_mfma_f32_16x16x32_f16(
                            b[nt], a[mt], acc[mt][nt], 0, 0, 0);
            } else {
#pragma unroll
                for (int mt = 0; mt < 4; mt++)
#pragma unroll
                    for (int nt = 0; nt < 4; nt++)
                        acc[mt][nt] = __builtin_amdgcn_mfma_f32_16x16x32_f16(
                            a[mt], b[nt], acc[mt][nt], 0, 0, 0);
            }
        }

        __syncthreads();   // drains t+1 stage (issued pre-compute -> covered);
                           // also fences buf reuse
    }

    if (swapped) {
        // acc[mt][nt]: element (s, d): s = m0+wm*64+mt*16+l15 (per-lane col),
        //                              d = n0+wn*64+nt*16+quad*4+r (rows, consecutive)
        float sc = (z == 0) ? 0.125f : 1.0f;
        _Float16* out = (z == 0) ? qh : kh;
#pragma unroll
        for (int nt = 0; nt < 4; nt++) {
            int d0 = n0 + wn * 64 + nt * 16 + quad * 4;
            int hh = d0 >> 6, dd = d0 & 63;
            floatx4 b4 = *(const floatx4*)&bias[d0];
#pragma unroll
            for (int mt = 0; mt < 4; mt++) {
                int s = m0 + wm * 64 + mt * 16 + l15;
                int b_ = s >> 10, ss = s & 1023;
                size_t off = ((size_t)(b_ * HEADS + hh)) * 65536 + (size_t)ss * 64 + dd;
                half4 hv;
#pragma unroll
                for (int r = 0; r < 4; r++)
                    hv[r] = (_Float16)((acc[mt][nt][r] + b4[r]) * sc);
                *(half4*)&out[off] = hv;
            }
        }
    } else {
        // acc[mt][nt]: element (s, d): d = n0+wn*64+nt*16+l15 (per-lane col),
        //                              s = m0+wm*64+mt*16+quad*4+r (rows, consecutive)
#pragma unroll
        for (int nt = 0; nt < 4; nt++) {
            int d = n0 + wn * 64 + nt * 16 + l15;
            int hh = d >> 6, dd = d & 63;
            float bv_ = bias[d];
#pragma unroll
            for (int mt = 0; mt < 4; mt++) {
                int s0 = m0 + wm * 64 + mt * 16 + quad * 4;
                int b_ = s0 >> 10, ss = s0 & 1023;
                size_t off = ((size_t)(b_ * HEADS + hh)) * 65536 + (size_t)dd * 1024 + ss;
                half4 hv;
#pragma unroll
                for (int r = 0; r < 4; r++)
                    hv[r] = (_Float16)(acc[mt][nt][r] + bv_);
                *(half4*)&vT[off] = hv;
            }
        }
    }
}

// ---------------------------------------------------------------------------
// Attention: one block = 256 q-rows of one (b,h); 64 q-rows per wave.
// grid (4, 16, 8), block 256. S^T = K*Q^T so P-writes are packed ds_write_b64;
// P lives in the dead Q-tile LDS region (per-wave 64x64 tile).
// K/V double-buffered (depth-1, proven pattern): stage kt+1 into buf^1 before
// computing kt; ONE __syncthreads per kt (was 2). K/V(0) staged alongside Q.
// LDS: Ks 16KB + Vs 16KB + QP 32KB = 64 KB -> 2 blocks/CU.
__global__ __launch_bounds__(256) void attn(
        const _Float16* __restrict__ qh, const _Float16* __restrict__ kh,
        const _Float16* __restrict__ vT, float* __restrict__ out) {
    __shared__ _Float16 Ks[2][4096];
    __shared__ _Float16 Vs[2][4096];
    __shared__ _Float16 QP[16384];
    int qt = blockIdx.x, h = blockIdx.y, b = blockIdx.z;
    size_t base = ((size_t)(b * HEADS + h)) * 65536;
    int tid = threadIdx.x, wid = tid >> 6, lane = tid & 63;
    int l15 = lane & 15, quad = lane >> 4;
    int rs = lane >> 3;
    int pg = (lane & 7) ^ rs;

    // stage Q tile [256][64] + K/V tile 0 (all drain at one barrier)
#pragma unroll
    for (int ii = 0; ii < 8; ii++) {
        int issue = wid * 8 + ii;
        int r = issue * 8 + rs;
        glds16(qh + base + (size_t)(qt * 256 + r) * 64 + pg * 8, &QP[issue * 512]);
    }
#pragma unroll
    for (int ii = 0; ii < 2; ii++) {
        int issue = wid * 2 + ii;
        int r = issue * 8 + rs;
        glds16(kh + base + (size_t)r * 64 + pg * 8, &Ks[0][issue * 512]);
        glds16(vT + base + (size_t)r * 1024 + pg * 8, &Vs[0][issue * 512]);
    }
    __syncthreads();
    half8 qf[4][2];
#pragma unroll
    for (int mt = 0; mt < 4; mt++)
#pragma unroll
        for (int kc = 0; kc < 2; kc++) {
            int row = wid * 64 + mt * 16 + l15;
            int pl = (kc * 4 + quad) ^ (l15 & 7);
            qf[mt][kc] = *(const half8*)&QP[row * 64 + pl * 8];
        }
    __syncthreads();   // all q-frag reads done before P overwrites the region

    floatx4 oacc[4][4] = {};
    float rden[4] = {0.f, 0.f, 0.f, 0.f};
    _Float16* Pw = &QP[wid * 4096];   // per-wave 64q x 64k P tile
                                      // layout: (k>>3)*512 + q*8 + (k&7)

    for (int kt = 0; kt < 16; kt++) {
        int cur = kt & 1;

        // ---- stage kt+1 first (covered by this tile's compute) ----
        if (kt < 15) {
#pragma unroll
            for (int ii = 0; ii < 2; ii++) {
                int issue = wid * 2 + ii;
                int r = issue * 8 + rs;
                glds16(kh + base + (size_t)((kt + 1) * 64 + r) * 64 + pg * 8,
                       &Ks[cur ^ 1][issue * 512]);
                glds16(vT + base + (size_t)r * 1024 + (kt + 1) * 64 + pg * 8,
                       &Vs[cur ^ 1][issue * 512]);
            }
        }

#pragma unroll
        for (int hf = 0; hf < 2; hf++) {
            // S^T = K * Q^T for 32 keys: D rows = key (consecutive), cols = query
            floatx4 sacc[2][4] = {};
#pragma unroll
            for (int kc = 0; kc < 2; kc++) {
                half8 kf[2];
#pragma unroll
                for (int kn2 = 0; kn2 < 2; kn2++) {
                    int kn = hf * 2 + kn2;
                    int pl = (kc * 4 + quad) ^ (l15 & 7);
                    kf[kn2] = *(const half8*)&Ks[cur][(kn * 16 + l15) * 64 + pl * 8];
                }
#pragma unroll
                for (int kn2 = 0; kn2 < 2; kn2++)
#pragma unroll
                    for (int mt = 0; mt < 4; mt++)
                        sacc[kn2][mt] = __builtin_amdgcn_mfma_f32_16x16x32_f16(
                            kf[kn2], qf[mt][kc], sacc[kn2][mt], 0, 0, 0);
            }
            // exp + packed P write: element (key kn*16+quad*4+r, query mt*16+l15)
#pragma unroll
            for (int kn2 = 0; kn2 < 2; kn2++) {
                int kn = hf * 2 + kn2;
#pragma unroll
                for (int mt = 0; mt < 4; mt++) {
                    half4 ph;
#pragma unroll
                    for (int r = 0; r < 4; r++) {
                        float p = __expf(sacc[kn2][mt][r]);
                        rden[mt] += p;
                        ph[r] = (_Float16)p;
                    }
                    *(half4*)&Pw[(kn * 2 + (quad >> 1)) * 512 + (mt * 16 + l15) * 8 +
                                 (quad & 1) * 4] = ph;
                }
            }
            // O += P * V for these 32 keys
            half8 af[4], vf[4];
#pragma unroll
            for (int mt = 0; mt < 4; mt++)
                af[mt] = *(const half8*)&Pw[(hf * 4 + quad) * 512 + (mt * 16 + l15) * 8];
#pragma unroll
            for (int dn = 0; dn < 4; dn++) {
                int pl = (hf * 4 + quad) ^ (l15 & 7);
                vf[dn] = *(const half8*)&Vs[cur][(dn * 16 + l15) * 64 + pl * 8];
            }
#pragma unroll
            for (int mt = 0; mt < 4; mt++)
#pragma unroll
                for (int dn = 0; dn < 4; dn++)
                    oacc[mt][dn] = __builtin_amdgcn_mfma_f32_16x16x32_f16(
                        af[mt], vf[dn], oacc[mt][dn], 0, 0, 0);
        }

        __syncthreads();   // drains kt+1 stage (covered) + fences buf reuse
    }

    // denominator: reduce across quads (each lane summed keys = quad*4+r pattern)
#pragma unroll
    for (int mt = 0; mt < 4; mt++) {
        float d = rden[mt];
        d += __shfl_xor(d, 16, 64);
        d += __shfl_xor(d, 32, 64);
        rden[mt] = 1.0f / (d + 1e-8f);
    }
    // oacc[mt][dn]: rows = q (mt*16+quad*4+r), cols = d (dn*16+l15)
#pragma unroll
    for (int mt = 0; mt < 4; mt++) {
#pragma unroll
        for (int r = 0; r < 4; r++) {
            float dinv = __shfl(rden[mt], quad * 4 + r, 16);
            int s = qt * 256 + wid * 64 + mt * 16 + quad * 4 + r;
#pragma unroll
            for (int dn = 0; dn < 4; dn++) {
                int col = h * 64 + dn * 16 + l15;
                out[((size_t)(b * SEQ + s)) * 1024 + col] = oacc[mt][dn][r] * dinv;
            }
        }
    }
}

// ---------------------------------------------------------------------------
extern "C" void kernel_launch(void* const* d_in, const int* in_sizes, int n_in,
                              void* d_out, int out_size, void* d_ws, size_t ws_size,
                              hipStream_t stream) {
    const float* Q  = (const float*)d_in[0];
    const float* K  = (const float*)d_in[1];
    const float* V  = (const float*)d_in[2];
    const float* Wq = (const float*)d_in[3];
    const float* bq = (const float*)d_in[4];
    const float* Wk = (const float*)d_in[5];
    const float* bk = (const float*)d_in[6];
    const float* Wv = (const float*)d_in[7];
    const float* bv = (const float*)d_in[8];
    float* out = (float*)d_out;

    char* ws = (char*)d_ws;
    const size_t TEN = (size_t)MTOT * DM * sizeof(_Float16);   // 16 MiB
    _Float16* qb  = (_Float16*)(ws);
    _Float16* kb  = (_Float16*)(ws + TEN);
    _Float16* vb  = (_Float16*)(ws + 2 * TEN);
    _Float16* qh  = (_Float16*)(ws + 3 * TEN);
    _Float16* kh  = (_Float16*)(ws + 4 * TEN);
    _Float16* vT  = (_Float16*)(ws + 5 * TEN);
    const size_t WTN = (size_t)DM * DM * sizeof(_Float16);     // 2 MiB
    _Float16* wqt = (_Float16*)(ws + 6 * TEN);
    _Float16* wkt = (_Float16*)(ws + 6 * TEN + WTN);
    _Float16* wvt = (_Float16*)(ws + 6 * TEN + 2 * WTN);

    prep<<<dim3(15360), 256, 0, stream>>>(Q, K, V, qb, kb, vb,
                                          Wq, Wk, Wv, wqt, wkt, wvt);
    proj_gemm<<<dim3(32, 8, 3), 512, 0, stream>>>(qb, kb, vb, wqt, wkt, wvt,
                                                  bq, bk, bv, qh, kh, vT);
    attn<<<dim3(4, 16, 8), 256, 0, stream>>>(qh, kh, vT, out);
}

// Round 10
// 277.605 us; speedup vs baseline: 1.0300x; 1.0300x over previous
//
#include <hip/hip_runtime.h>
#include <stdint.h>

#define DM 1024      // d_model
#define HEADS 16
#define BATCH 8
#define SEQ 1024
#define MTOT 8192    // BATCH*SEQ

typedef _Float16 half8 __attribute__((ext_vector_type(8)));
typedef _Float16 half4 __attribute__((ext_vector_type(4)));
typedef float floatx4 __attribute__((ext_vector_type(4)));

// async global->LDS, 16B per lane. lds dest must be wave-uniform base; HW adds lane*16.
__device__ __forceinline__ void glds16(const void* g, void* l) {
    __builtin_amdgcn_global_load_lds(
        (const __attribute__((address_space(1))) void*)g,
        (__attribute__((address_space(3))) void*)l, 16, 0, 0);
}

// ---------------------------------------------------------------------------
// Fused prep: blocks [0,12288) convert Q/K/V fp32->fp16 (8 elems/thread);
// blocks [12288,15360) transpose+convert W[K][N] fp32 -> Wt[N][K] fp16.
__global__ __launch_bounds__(256) void prep(
        const float* __restrict__ Q, const float* __restrict__ K,
        const float* __restrict__ V,
        _Float16* __restrict__ qb, _Float16* __restrict__ kb, _Float16* __restrict__ vb,
        const float* __restrict__ Wq, const float* __restrict__ Wk,
        const float* __restrict__ Wv,
        _Float16* __restrict__ wqt, _Float16* __restrict__ wkt, _Float16* __restrict__ wvt) {
    __shared__ float t[32][33];
    int bid = blockIdx.x, tid = threadIdx.x;
    if (bid < 12288) {
        int ten = bid >> 12;              // 0,1,2
        int bx  = bid & 4095;
        const float* src = ten == 0 ? Q : (ten == 1 ? K : V);
        _Float16* dst    = ten == 0 ? qb : (ten == 1 ? kb : vb);
        size_t i = ((size_t)bx * 256 + tid) * 8;
        float4 a = *(const float4*)(src + i);
        float4 b = *(const float4*)(src + i + 4);
        half8 h;
        h[0] = (_Float16)a.x; h[1] = (_Float16)a.y; h[2] = (_Float16)a.z; h[3] = (_Float16)a.w;
        h[4] = (_Float16)b.x; h[5] = (_Float16)b.y; h[6] = (_Float16)b.z; h[7] = (_Float16)b.w;
        *(half8*)(dst + i) = h;
    } else {
        int wb = bid - 12288;             // [0, 3072)
        int z  = wb >> 10;                // 0,1,2
        int rem = wb & 1023;
        const float* W = z == 0 ? Wq : (z == 1 ? Wk : Wv);
        _Float16* Wt   = z == 0 ? wqt : (z == 1 ? wkt : wvt);
        int k0 = (rem & 31) * 32, n0 = (rem >> 5) * 32;
        int tx = tid & 31, ty = tid >> 5;
#pragma unroll
        for (int i = 0; i < 4; i++)
            t[ty + i * 8][tx] = W[(size_t)(k0 + ty + i * 8) * DM + n0 + tx];
        __syncthreads();
#pragma unroll
        for (int i = 0; i < 4; i++)
            Wt[(size_t)(n0 + ty + i * 8) * DM + k0 + tx] = (_Float16)t[tx][ty + i * 8];
    }
}

// ---------------------------------------------------------------------------
// Projection GEMM: C[8192,1024] = A[8192,1024] @ W[1024,1024] + bias.
// grid (64, 8, 3), block 256 (4 waves, 2x2 of 64x64 each) -- r7 proven config.
// Depth-1 glds16-only dbuf: per K-tile issue stage(t+1) into buf^1 FIRST,
// then frag-read + 32 MFMA on buf, then ONE __syncthreads. 64KB LDS ->
// 2 blocks/CU: cross-block overlap hides each block's barrier drain
// (r9 lesson: one 8-wave 96KB block = 1 blk/CU regressed 72.5->91 us;
// per-block barriers with >=2 blocks/CU are the latency hider).
// z<2: MFMA operand order swapped (A-op = W-frag) so accumulator rows = d
//      (consecutive) -> packed 8B stores to [b][h][s][d].
// z=2: original order, accumulator rows = s -> packed 8B stores to vT [b][h][d][s].
__global__ __launch_bounds__(256) void proj_gemm(
        const _Float16* __restrict__ qb, const _Float16* __restrict__ kb,
        const _Float16* __restrict__ vb,
        const _Float16* __restrict__ wqt, const _Float16* __restrict__ wkt,
        const _Float16* __restrict__ wvt,
        const float* __restrict__ bq, const float* __restrict__ bk,
        const float* __restrict__ bv,
        _Float16* __restrict__ qh, _Float16* __restrict__ kh, _Float16* __restrict__ vT) {
    __shared__ _Float16 As[2][128 * 64];
    __shared__ _Float16 Bs[2][128 * 64];
    int z = blockIdx.z;
    const _Float16* A  = z == 0 ? qb : (z == 1 ? kb : vb);
    const _Float16* Bw = z == 0 ? wqt : (z == 1 ? wkt : wvt);
    const float* bias  = z == 0 ? bq : (z == 1 ? bk : bv);
    int m0 = blockIdx.x * 128, n0 = blockIdx.y * 128;
    int tid = threadIdx.x, wid = tid >> 6, lane = tid & 63;
    int l15 = lane & 15, quad = lane >> 4;
    int wm = wid >> 1, wn = wid & 1;
    bool swapped = (z < 2);

    int rbase = wid * 32 + (lane >> 3);   // staged row: (wid*4+ii)*8 + (lane>>3)
    int pg = (lane & 7) ^ (lane >> 3);    // pre-swizzled global 16B chunk

    floatx4 acc[4][4] = {};

    // ---- prologue: stage K-tile 0 into buf 0 ----
#pragma unroll
    for (int ii = 0; ii < 4; ii++) {
        int rr = rbase + ii * 8;
        glds16(A  + (size_t)(m0 + rr) * DM + pg * 8, &As[0][(wid * 4 + ii) * 512]);
        glds16(Bw + (size_t)(n0 + rr) * DM + pg * 8, &Bs[0][(wid * 4 + ii) * 512]);
    }
    __syncthreads();

    for (int t = 0; t < 16; t++) {
        int cur = t & 1;

        // ---- issue next-tile stage first (latency hides under compute) ----
        if (t < 15) {
            int k0 = (t + 1) * 64;
#pragma unroll
            for (int ii = 0; ii < 4; ii++) {
                int rr = rbase + ii * 8;
                glds16(A  + (size_t)(m0 + rr) * DM + k0 + pg * 8,
                       &As[cur ^ 1][(wid * 4 + ii) * 512]);
                glds16(Bw + (size_t)(n0 + rr) * DM + k0 + pg * 8,
                       &Bs[cur ^ 1][(wid * 4 + ii) * 512]);
            }
        }

        // ---- compute current tile ----
#pragma unroll
        for (int kc = 0; kc < 2; kc++) {
            half8 a[4], b[4];
#pragma unroll
            for (int mt = 0; mt < 4; mt++) {
                int row = wm * 64 + mt * 16 + l15;
                int pl = (kc * 4 + quad) ^ (l15 & 7);
                a[mt] = *(const half8*)&As[cur][row * 64 + pl * 8];
            }
#pragma unroll
            for (int nt = 0; nt < 4; nt++) {
                int row = wn * 64 + nt * 16 + l15;
                int pl = (kc * 4 + quad) ^ (l15 & 7);
                b[nt] = *(const half8*)&Bs[cur][row * 64 + pl * 8];
            }
            if (swapped) {
#pragma unroll
                for (int mt = 0; mt < 4; mt++)
#pragma unroll
                    for (int nt = 0; nt < 4; nt++)
                        acc[mt][nt] = __builtin_amdgcn_mfma_f32_16x16x32_f16(
                            b[nt], a[mt], acc[mt][nt], 0, 0, 0);
            } else {
#pragma unroll
                for (int mt = 0; mt < 4; mt++)
#pragma unroll
                    for (int nt = 0; nt < 4; nt++)
                        acc[mt][nt] = __builtin_amdgcn_mfma_f32_16x16x32_f16(
                            a[mt], b[nt], acc[mt][nt], 0, 0, 0);
            }
        }

        __syncthreads();   // drains t+1 stage (issued pre-compute -> covered);
                           // also fences buf reuse
    }

    if (swapped) {
        // acc[mt][nt]: element (s, d): s = m0+wm*64+mt*16+l15 (per-lane col),
        //                              d = n0+wn*64+nt*16+quad*4+r (rows, consecutive)
        float sc = (z == 0) ? 0.125f : 1.0f;
        _Float16* out = (z == 0) ? qh : kh;
#pragma unroll
        for (int nt = 0; nt < 4; nt++) {
            int d0 = n0 + wn * 64 + nt * 16 + quad * 4;
            int hh = d0 >> 6, dd = d0 & 63;
            floatx4 b4 = *(const floatx4*)&bias[d0];
#pragma unroll
            for (int mt = 0; mt < 4; mt++) {
                int s = m0 + wm * 64 + mt * 16 + l15;
                int b_ = s >> 10, ss = s & 1023;
                size_t off = ((size_t)(b_ * HEADS + hh)) * 65536 + (size_t)ss * 64 + dd;
                half4 hv;
#pragma unroll
                for (int r = 0; r < 4; r++)
                    hv[r] = (_Float16)((acc[mt][nt][r] + b4[r]) * sc);
                *(half4*)&out[off] = hv;
            }
        }
    } else {
        // acc[mt][nt]: element (s, d): d = n0+wn*64+nt*16+l15 (per-lane col),
        //                              s = m0+wm*64+mt*16+quad*4+r (rows, consecutive)
#pragma unroll
        for (int nt = 0; nt < 4; nt++) {
            int d = n0 + wn * 64 + nt * 16 + l15;
            int hh = d >> 6, dd = d & 63;
            float bv_ = bias[d];
#pragma unroll
            for (int mt = 0; mt < 4; mt++) {
                int s0 = m0 + wm * 64 + mt * 16 + quad * 4;
                int b_ = s0 >> 10, ss = s0 & 1023;
                size_t off = ((size_t)(b_ * HEADS + hh)) * 65536 + (size_t)dd * 1024 + ss;
                half4 hv;
#pragma unroll
                for (int r = 0; r < 4; r++)
                    hv[r] = (_Float16)(acc[mt][nt][r] + bv_);
                *(half4*)&vT[off] = hv;
            }
        }
    }
}

// ---------------------------------------------------------------------------
// Attention: one block = 256 q-rows of one (b,h); 64 q-rows per wave.
// grid (4, 16, 8), block 256. S^T = K*Q^T so P-writes are packed ds_write_b64;
// P lives in the dead Q-tile LDS region (per-wave 64x64 tile).
// K/V double-buffered (depth-1, proven r9: ~-9us): stage kt+1 into buf^1
// before computing kt; ONE __syncthreads per kt (was 2). K/V(0) staged with Q.
// LDS: Ks 16KB + Vs 16KB + QP 32KB = 64 KB -> 2 blocks/CU.
__global__ __launch_bounds__(256) void attn(
        const _Float16* __restrict__ qh, const _Float16* __restrict__ kh,
        const _Float16* __restrict__ vT, float* __restrict__ out) {
    __shared__ _Float16 Ks[2][4096];
    __shared__ _Float16 Vs[2][4096];
    __shared__ _Float16 QP[16384];
    int qt = blockIdx.x, h = blockIdx.y, b = blockIdx.z;
    size_t base = ((size_t)(b * HEADS + h)) * 65536;
    int tid = threadIdx.x, wid = tid >> 6, lane = tid & 63;
    int l15 = lane & 15, quad = lane >> 4;
    int rs = lane >> 3;
    int pg = (lane & 7) ^ rs;

    // stage Q tile [256][64] + K/V tile 0 (all drain at one barrier)
#pragma unroll
    for (int ii = 0; ii < 8; ii++) {
        int issue = wid * 8 + ii;
        int r = issue * 8 + rs;
        glds16(qh + base + (size_t)(qt * 256 + r) * 64 + pg * 8, &QP[issue * 512]);
    }
#pragma unroll
    for (int ii = 0; ii < 2; ii++) {
        int issue = wid * 2 + ii;
        int r = issue * 8 + rs;
        glds16(kh + base + (size_t)r * 64 + pg * 8, &Ks[0][issue * 512]);
        glds16(vT + base + (size_t)r * 1024 + pg * 8, &Vs[0][issue * 512]);
    }
    __syncthreads();
    half8 qf[4][2];
#pragma unroll
    for (int mt = 0; mt < 4; mt++)
#pragma unroll
        for (int kc = 0; kc < 2; kc++) {
            int row = wid * 64 + mt * 16 + l15;
            int pl = (kc * 4 + quad) ^ (l15 & 7);
            qf[mt][kc] = *(const half8*)&QP[row * 64 + pl * 8];
        }
    __syncthreads();   // all q-frag reads done before P overwrites the region

    floatx4 oacc[4][4] = {};
    float rden[4] = {0.f, 0.f, 0.f, 0.f};
    _Float16* Pw = &QP[wid * 4096];   // per-wave 64q x 64k P tile
                                      // layout: (k>>3)*512 + q*8 + (k&7)

    for (int kt = 0; kt < 16; kt++) {
        int cur = kt & 1;

        // ---- stage kt+1 first (covered by this tile's compute) ----
        if (kt < 15) {
#pragma unroll
            for (int ii = 0; ii < 2; ii++) {
                int issue = wid * 2 + ii;
                int r = issue * 8 + rs;
                glds16(kh + base + (size_t)((kt + 1) * 64 + r) * 64 + pg * 8,
                       &Ks[cur ^ 1][issue * 512]);
                glds16(vT + base + (size_t)r * 1024 + (kt + 1) * 64 + pg * 8,
                       &Vs[cur ^ 1][issue * 512]);
            }
        }

#pragma unroll
        for (int hf = 0; hf < 2; hf++) {
            // S^T = K * Q^T for 32 keys: D rows = key (consecutive), cols = query
            floatx4 sacc[2][4] = {};
#pragma unroll
            for (int kc = 0; kc < 2; kc++) {
                half8 kf[2];
#pragma unroll
                for (int kn2 = 0; kn2 < 2; kn2++) {
                    int kn = hf * 2 + kn2;
                    int pl = (kc * 4 + quad) ^ (l15 & 7);
                    kf[kn2] = *(const half8*)&Ks[cur][(kn * 16 + l15) * 64 + pl * 8];
                }
#pragma unroll
                for (int kn2 = 0; kn2 < 2; kn2++)
#pragma unroll
                    for (int mt = 0; mt < 4; mt++)
                        sacc[kn2][mt] = __builtin_amdgcn_mfma_f32_16x16x32_f16(
                            kf[kn2], qf[mt][kc], sacc[kn2][mt], 0, 0, 0);
            }
            // exp + packed P write: element (key kn*16+quad*4+r, query mt*16+l15)
#pragma unroll
            for (int kn2 = 0; kn2 < 2; kn2++) {
                int kn = hf * 2 + kn2;
#pragma unroll
                for (int mt = 0; mt < 4; mt++) {
                    half4 ph;
#pragma unroll
                    for (int r = 0; r < 4; r++) {
                        float p = __expf(sacc[kn2][mt][r]);
                        rden[mt] += p;
                        ph[r] = (_Float16)p;
                    }
                    *(half4*)&Pw[(kn * 2 + (quad >> 1)) * 512 + (mt * 16 + l15) * 8 +
                                 (quad & 1) * 4] = ph;
                }
            }
            // O += P * V for these 32 keys
            half8 af[4], vf[4];
#pragma unroll
            for (int mt = 0; mt < 4; mt++)
                af[mt] = *(const half8*)&Pw[(hf * 4 + quad) * 512 + (mt * 16 + l15) * 8];
#pragma unroll
            for (int dn = 0; dn < 4; dn++) {
                int pl = (hf * 4 + quad) ^ (l15 & 7);
                vf[dn] = *(const half8*)&Vs[cur][(dn * 16 + l15) * 64 + pl * 8];
            }
#pragma unroll
            for (int mt = 0; mt < 4; mt++)
#pragma unroll
                for (int dn = 0; dn < 4; dn++)
                    oacc[mt][dn] = __builtin_amdgcn_mfma_f32_16x16x32_f16(
                        af[mt], vf[dn], oacc[mt][dn], 0, 0, 0);
        }

        __syncthreads();   // drains kt+1 stage (covered) + fences buf reuse
    }

    // denominator: reduce across quads (each lane summed keys = quad*4+r pattern)
#pragma unroll
    for (int mt = 0; mt < 4; mt++) {
        float d = rden[mt];
        d += __shfl_xor(d, 16, 64);
        d += __shfl_xor(d, 32, 64);
        rden[mt] = 1.0f / (d + 1e-8f);
    }
    // oacc[mt][dn]: rows = q (mt*16+quad*4+r), cols = d (dn*16+l15)
#pragma unroll
    for (int mt = 0; mt < 4; mt++) {
#pragma unroll
        for (int r = 0; r < 4; r++) {
            float dinv = __shfl(rden[mt], quad * 4 + r, 16);
            int s = qt * 256 + wid * 64 + mt * 16 + quad * 4 + r;
#pragma unroll
            for (int dn = 0; dn < 4; dn++) {
                int col = h * 64 + dn * 16 + l15;
                out[((size_t)(b * SEQ + s)) * 1024 + col] = oacc[mt][dn][r] * dinv;
            }
        }
    }
}

// ---------------------------------------------------------------------------
extern "C" void kernel_launch(void* const* d_in, const int* in_sizes, int n_in,
                              void* d_out, int out_size, void* d_ws, size_t ws_size,
                              hipStream_t stream) {
    const float* Q  = (const float*)d_in[0];
    const float* K  = (const float*)d_in[1];
    const float* V  = (const float*)d_in[2];
    const float* Wq = (const float*)d_in[3];
    const float* bq = (const float*)d_in[4];
    const float* Wk = (const float*)d_in[5];
    const float* bk = (const float*)d_in[6];
    const float* Wv = (const float*)d_in[7];
    const float* bv = (const float*)d_in[8];
    float* out = (float*)d_out;

    char* ws = (char*)d_ws;
    const size_t TEN = (size_t)MTOT * DM * sizeof(_Float16);   // 16 MiB
    _Float16* qb  = (_Float16*)(ws);
    _Float16* kb  = (_Float16*)(ws + TEN);
    _Float16* vb  = (_Float16*)(ws + 2 * TEN);
    _Float16* qh  = (_Float16*)(ws + 3 * TEN);
    _Float16* kh  = (_Float16*)(ws + 4 * TEN);
    _Float16* vT  = (_Float16*)(ws + 5 * TEN);
    const size_t WTN = (size_t)DM * DM * sizeof(_Float16);     // 2 MiB
    _Float16* wqt = (_Float16*)(ws + 6 * TEN);
    _Float16* wkt = (_Float16*)(ws + 6 * TEN + WTN);
    _Float16* wvt = (_Float16*)(ws + 6 * TEN + 2 * WTN);

    prep<<<dim3(15360), 256, 0, stream>>>(Q, K, V, qb, kb, vb,
                                          Wq, Wk, Wv, wqt, wkt, wvt);
    proj_gemm<<<dim3(64, 8, 3), 256, 0, stream>>>(qb, kb, vb, wqt, wkt, wvt,
                                                  bq, bk, bv, qh, kh, vT);
    attn<<<dim3(4, 16, 8), 256, 0, stream>>>(qh, kh, vT, out);
}